// Round 10
// baseline (938.000 us; speedup 1.0000x reference)
//
#include <hip/hip_runtime.h>
#include <hip/hip_bf16.h>
#include <math.h>

// Problem constants
#define E_ 8
#define D_ 2048
#define I_ 4096
#define TOPK_ 2
#define N_ 4096
#define NPAIR (N_*TOPK_)
#define PADMAX 10240
#define MAXTB256 40
#define NIB 16           // GEMM by-rows per gu8 half (I/2 / 128)
#define CVTX 16          // K2 extra bx columns: (40+16)*16 = 896 = 3.5 rounds
#define CH_X   (1L<<20)  // x chunks (8 elems each)
#define CH_HALF (1L<<22) // per-matrix half-I chunks

typedef __attribute__((ext_vector_type(8))) short s8v;
typedef __attribute__((ext_vector_type(8))) unsigned short us8;
typedef __attribute__((ext_vector_type(4))) float f32x4;
typedef const __attribute__((address_space(1))) void* gvp;
typedef __attribute__((address_space(3))) void* lvp;

__device__ __forceinline__ unsigned short f2bf(float f) {
  union { float f; unsigned int u; } c; c.f = f;
  unsigned int u = c.u;
  u += 0x7fffu + ((u >> 16) & 1u);
  return (unsigned short)(u >> 16);
}

__device__ __forceinline__ void cvt_chunk(const float* __restrict__ src,
                                          unsigned short* __restrict__ dst,
                                          size_t off) {
  float4 a = *(const float4*)(src + off);
  float4 b = *(const float4*)(src + off + 4);
  us8 o;
  o[0]=f2bf(a.x); o[1]=f2bf(a.y); o[2]=f2bf(a.z); o[3]=f2bf(a.w);
  o[4]=f2bf(b.x); o[5]=f2bf(b.y); o[6]=f2bf(b.z); o[7]=f2bf(b.w);
  *(us8*)(dst + off) = o;
}

// convert chunk of an I-half region of a [E][I][D] matrix (ihalf = 0/1)
__device__ __forceinline__ void cvt_half(const float* __restrict__ src,
                                         unsigned short* __restrict__ dst,
                                         long chunk, int ihalf) {
  long f = chunk << 3;
  int e = (int)(f >> 22);
  long r = f & ((1L << 22) - 1);
  size_t off = ((size_t)e << 23) + ((size_t)ihalf << 22) + (size_t)r;
  cvt_chunk(src, dst, off);
}

// ---------------- Head: route (block 0) + x cvt + wg/wu half0 cvt ----------------
__global__ __launch_bounds__(512)
void head_kernel(const int* __restrict__ idx, const float* __restrict__ ew,
                 int* cnt, int* offs, int* tb, int* ntb,
                 int* perm, float* wgt,
                 const float* __restrict__ x, unsigned short* __restrict__ xb,
                 const float* __restrict__ wg, unsigned short* __restrict__ wgb,
                 const float* __restrict__ wu, unsigned short* __restrict__ wub)
{
  if (blockIdx.x == 0) {
    __shared__ int scnt[E_], soff[E_ + 1], scur[E_];
    int t = threadIdx.x;
    if (t < E_) scnt[t] = 0;
    __syncthreads();
    for (int p = t; p < NPAIR; p += blockDim.x) atomicAdd(&scnt[idx[p]], 1);
    __syncthreads();
    if (t == 0) {
      int o = 0;
      for (int e = 0; e < E_; e++) {
        soff[e] = o; scur[e] = o;
        o += ((scnt[e] + 255) / 256) * 256;
      }
      soff[E_] = o;
      int T = 0;
      for (int e = 0; e < E_; e++) {
        int nb = (scnt[e] + 255) / 256;
        for (int rb = 0; rb < nb; rb++) tb[T++] = (e << 16) | rb;
      }
      *ntb = T;
      for (int e = 0; e < E_; e++) { cnt[e] = scnt[e]; offs[e] = soff[e]; }
      offs[E_] = o;
    }
    __syncthreads();
    for (int e = 0; e < E_; e++) {
      int start = soff[e] + scnt[e], end = soff[e + 1];
      for (int s = start + t; s < end; s += blockDim.x) { perm[s] = -1; wgt[s] = 0.f; }
    }
    __syncthreads();
    for (int p = t; p < NPAIR; p += blockDim.x) {
      int e = idx[p];
      int pos = atomicAdd(&scur[e], 1);
      perm[pos] = p / TOPK_;
      wgt[pos]  = ew[p];
    }
    return;
  }
  const long TOTAL = CH_X + 2 * CH_HALF;
  long c0 = (long)(blockIdx.x - 1) * 512 + threadIdx.x;
  long stride = (long)(gridDim.x - 1) * 512;
  for (long c = c0; c < TOTAL; c += stride) {
    if (c < CH_X) cvt_chunk(x, xb, (size_t)c << 3);
    else if (c < CH_X + CH_HALF) cvt_half(wg, wgb, c - CH_X, 0);
    else cvt_half(wu, wub, c - CH_X - CH_HALF, 0);
  }
}

// =================== 8-phase 256-tile grouped GEMM machinery (round-3/6 proven) ===================
#define A_SLAB(P,KH) (((P)*2+(KH))*8192)
#define B_SLAB(P,KH) (32768 + ((P)*2+(KH))*8192)

#define SB  __builtin_amdgcn_sched_barrier(0)
#define BARR __builtin_amdgcn_s_barrier()
#define VMW(N) asm volatile("s_waitcnt vmcnt(" #N ")" ::: "memory")
#define LGK asm volatile("s_waitcnt lgkmcnt(0)" ::: "memory")
#define PRIO1 __builtin_amdgcn_s_setprio(1)
#define PRIO0 __builtin_amdgcn_s_setprio(0)

#define LOAD_A(P,KH,MH) { \
  const unsigned short* ap_ = &smem[A_SLAB(P,KH) + aBase + (MH)*2048]; \
  af[0] = *(const s8v*)(ap_);      af[1] = *(const s8v*)(ap_+512); \
  af[2] = *(const s8v*)(ap_+1024); af[3] = *(const s8v*)(ap_+1536); }

#define LOAD_B(P,KH) { \
  const unsigned short* bp_ = &smem[B_SLAB(P,KH) + bBase]; \
  bf[0] = *(const s8v*)(bp_);      bf[1] = *(const s8v*)(bp_+512); \
  bf[2] = *(const s8v*)(bp_+1024); bf[3] = *(const s8v*)(bp_+1536); }

#define STAGE_A(T,KH,P) { \
  __builtin_amdgcn_global_load_lds((gvp)(aptr0 + (T)*64 + (KH)*32), (lvp)(&smem[A_SLAB(P,KH) + (w*2+0)*512]), 16, 0, 0); \
  __builtin_amdgcn_global_load_lds((gvp)(aptr1 + (T)*64 + (KH)*32), (lvp)(&smem[A_SLAB(P,KH) + (w*2+1)*512]), 16, 0, 0); }

#define STAGE_B(T,KH,P) { \
  __builtin_amdgcn_global_load_lds((gvp)(bptr0 + (T)*64 + (KH)*32), (lvp)(&smem[B_SLAB(P,KH) + (w*2+0)*512]), 16, 0, 0); \
  __builtin_amdgcn_global_load_lds((gvp)(bptr1 + (T)*64 + (KH)*32), (lvp)(&smem[B_SLAB(P,KH) + (w*2+1)*512]), 16, 0, 0); }

#define MFMA16(MH) { \
  _Pragma("unroll") for (int m_ = 0; m_ < 4; m_++) \
    _Pragma("unroll") for (int n_ = 0; n_ < 4; n_++) \
      acc[(MH)*4+m_][n_] = __builtin_amdgcn_mfma_f32_16x16x32_bf16(af[m_], bf[n_], acc[(MH)*4+m_][n_], 0, 0, 0); }

#define TILE_PHASES(T, P, Pn, NT_) { \
  if (T) { VMW(4); SB; } \
  LOAD_B(P, 0); LOAD_A(P, 0, 0); \
  if ((T) + 1 < (NT_)) { STAGE_A((T)+1, 1, Pn); } \
  SB; BARR; LGK; SB; \
  PRIO1; MFMA16(0); PRIO0; SB; BARR; SB; \
  LOAD_A(P, 0, 1); \
  if ((T) + 1 < (NT_)) { STAGE_B((T)+1, 1, Pn); } \
  SB; BARR; LGK; SB; \
  PRIO1; MFMA16(1); PRIO0; SB; BARR; SB; \
  if ((T) == (NT_) - 1) { VMW(0); SB; } else { VMW(4); SB; } \
  LOAD_B(P, 1); LOAD_A(P, 1, 0); \
  if ((T) + 2 < (NT_)) { STAGE_A((T)+2, 0, P); } \
  SB; BARR; LGK; SB; \
  PRIO1; MFMA16(0); PRIO0; SB; BARR; SB; \
  LOAD_A(P, 1, 1); \
  if ((T) + 2 < (NT_)) { STAGE_B((T)+2, 0, P); } \
  SB; BARR; LGK; SB; \
  PRIO1; MFMA16(1); PRIO0; SB; BARR; SB; }

#define K_LOOP(NT_) { \
  STAGE_A(0,0,0); STAGE_B(0,0,0); STAGE_A(0,1,0); STAGE_B(0,1,0); \
  STAGE_A(1,0,1); STAGE_B(1,0,1); \
  VMW(8); SB; BARR; SB; \
  _Pragma("unroll 1") \
  for (int tt = 0; tt < (NT_)/2; ++tt) { \
    TILE_PHASES(2*tt,   0, 1, NT_); \
    TILE_PHASES(2*tt+1, 1, 0, NT_); \
  } }

// ---------------- gate+up half-I GEMM + appended converter blocks ----------------
__global__ __launch_bounds__(512, 2)
void gu8_kernel(const unsigned short* __restrict__ xb,
                const unsigned short* __restrict__ wgb,
                const unsigned short* __restrict__ wub,
                const int* __restrict__ tb, const int* __restrict__ ntb,
                const int* __restrict__ offs, const int* __restrict__ perm,
                unsigned short* __restrict__ H,
                int i_base, int cvt_mode,
                const float* __restrict__ cs0, unsigned short* __restrict__ cd0,
                const float* __restrict__ cs1, unsigned short* __restrict__ cd1)
{
  __shared__ unsigned short smem[65536];   // 128 KB

  if (blockIdx.x >= MAXTB256) {
    // converter blocks (K2 only): wg half1 + wu half1
    long cid = (long)(blockIdx.x - MAXTB256) + (long)CVTX * blockIdx.y;
    long c0 = cid * 512 + threadIdx.x;
    long stride = (long)CVTX * NIB * 512;
    if (cvt_mode == 1) {
      for (long c = c0; c < 2 * CH_HALF; c += stride) {
        if (c < CH_HALF) cvt_half(cs0, cd0, c, 1);
        else cvt_half(cs1, cd1, c - CH_HALF, 1);
      }
    }
    return;
  }

  // XCD swizzle, by-major decode (proven round-3/6): XCD owns 2 by-cols x all bx
  int lid = blockIdx.y * MAXTB256 + blockIdx.x;
  int sid = (lid & 7) * (MAXTB256 * NIB / 8) + (lid >> 3);
  int bx = sid % MAXTB256;
  int by = sid / MAXTB256;
  if (bx >= *ntb) return;
  int ent = tb[bx];
  int e = ent >> 16, rb = ent & 0xffff;
  int slotbase = offs[e] + rb * 256;
  int i0 = i_base + by * 128;

  int tid = threadIdx.x, lane = tid & 63, w = tid >> 6;
  int wr = w >> 2, wc = w & 3;

  int cS = (lane & 7) ^ (lane >> 3);
  int rrS = 2 * (lane >> 3) + (cS >> 2);
  int kcS = (cS & 3) * 8;
  int ar0 = (w * 2 + 0) * 16 + rrS;
  int tk0 = perm[slotbase + ar0];       if (tk0 < 0) tk0 = 0;
  int tk1 = perm[slotbase + ar0 + 16];  if (tk1 < 0) tk1 = 0;
  const unsigned short* aptr0 = xb + (size_t)tk0 * D_ + kcS;
  const unsigned short* aptr1 = xb + (size_t)tk1 * D_ + kcS;
  const unsigned short* bptr0 = wgb + ((size_t)e * I_ + i0 + w * 16 + rrS) * D_ + kcS;
  const unsigned short* bptr1 = wub + ((size_t)e * I_ + i0 + w * 16 + rrS) * D_ + kcS;

  int hl = (lane & 15) >> 1;
  int pA = (((lane & 1) * 4 + (lane >> 4)) ^ hl) * 8;
  int aBase = wr * 4096 + hl * 64 + pA;
  int bBase = wc * 2048 + hl * 64 + pA;

  s8v af[4], bf[4];
  f32x4 acc[8][4];
#pragma unroll
  for (int m = 0; m < 8; m++)
#pragma unroll
    for (int n = 0; n < 4; n++) acc[m][n] = f32x4{0.f,0.f,0.f,0.f};

  K_LOOP(32);   // D_/64

#pragma unroll
  for (int m = 0; m < 8; m++) {
#pragma unroll
    for (int r = 0; r < 4; r++) {
      int row = wr * 128 + m * 16 + (lane >> 4) * 4 + r;
      size_t hbase = (size_t)(slotbase + row) * I_ + i0 + (lane & 15);
#pragma unroll
      for (int pr = 0; pr < 2; pr++) {
        float g = acc[m][pr*2][r];
        float u = acc[m][pr*2+1][r];
        float h = (g / (1.0f + __expf(-g))) * u;
        H[hbase + (wc * 2 + pr) * 16] = f2bf(h);
      }
    }
  }
}

// ---------------- down: 256 slots x 128 D-cols, fp32 wd direct, K-split x2 ----------------
// B slab = 128 rows x 32 K x fp32 = 16 KB: same 2 gl_lds/wave/slab as bf16 template
// -> identical vmcnt walk. LDS byte = r*128 + (c^(r&7))*16; staging source
// pre-swizzled with (lane&7)^(lane>>3) (verified 2-way-bank free).
#define STAGE_B32(T,KH,P) { \
  __builtin_amdgcn_global_load_lds((gvp)(bptr0 + (T)*64 + (KH)*32), (lvp)(&smem[B_SLAB(P,KH) + 0*4096 + w*512]), 16, 0, 0); \
  __builtin_amdgcn_global_load_lds((gvp)(bptr1 + (T)*64 + (KH)*32), (lvp)(&smem[B_SLAB(P,KH) + 1*4096 + w*512]), 16, 0, 0); }

#define LOAD_B32(P,KH) { \
  const float* fb_ = (const float*)&smem[B_SLAB(P,KH)]; \
  _Pragma("unroll") for (int n_ = 0; n_ < 2; n_++) { \
    int r_ = wc * 32 + n_ * 16 + (lane & 15); \
    int s_ = r_ & 7; int ks_ = (lane >> 4) * 2; \
    float4 u_ = *(const float4*)(fb_ + r_ * 32 + ((ks_    ) ^ s_) * 4); \
    float4 v_ = *(const float4*)(fb_ + r_ * 32 + ((ks_ + 1) ^ s_) * 4); \
    s8v t_; \
    t_[0]=(short)f2bf(u_.x); t_[1]=(short)f2bf(u_.y); t_[2]=(short)f2bf(u_.z); t_[3]=(short)f2bf(u_.w); \
    t_[4]=(short)f2bf(v_.x); t_[5]=(short)f2bf(v_.y); t_[6]=(short)f2bf(v_.z); t_[7]=(short)f2bf(v_.w); \
    bf[n_] = t_; } }

#define MFMA8(MH) { \
  _Pragma("unroll") for (int m_ = 0; m_ < 4; m_++) \
    _Pragma("unroll") for (int n_ = 0; n_ < 2; n_++) \
      acc[(MH)*4+m_][n_] = __builtin_amdgcn_mfma_f32_16x16x32_bf16(af[m_], bf[n_], acc[(MH)*4+m_][n_], 0, 0, 0); }

#define TILE_PHASES32(T, P, Pn, NT_) { \
  if (T) { VMW(4); SB; } \
  LOAD_B32(P, 0); LOAD_A(P, 0, 0); \
  if ((T) + 1 < (NT_)) { STAGE_A((T)+1, 1, Pn); } \
  SB; BARR; LGK; SB; \
  PRIO1; MFMA8(0); PRIO0; SB; BARR; SB; \
  LOAD_A(P, 0, 1); \
  if ((T) + 1 < (NT_)) { STAGE_B32((T)+1, 1, Pn); } \
  SB; BARR; LGK; SB; \
  PRIO1; MFMA8(1); PRIO0; SB; BARR; SB; \
  if ((T) == (NT_) - 1) { VMW(0); SB; } else { VMW(4); SB; } \
  LOAD_B32(P, 1); LOAD_A(P, 1, 0); \
  if ((T) + 2 < (NT_)) { STAGE_A((T)+2, 0, P); } \
  SB; BARR; LGK; SB; \
  PRIO1; MFMA8(0); PRIO0; SB; BARR; SB; \
  LOAD_A(P, 1, 1); \
  if ((T) + 2 < (NT_)) { STAGE_B32((T)+2, 0, P); } \
  SB; BARR; LGK; SB; \
  PRIO1; MFMA8(1); PRIO0; SB; BARR; SB; }

#define K_LOOP32(NT_) { \
  STAGE_A(0,0,0); STAGE_B32(0,0,0); STAGE_A(0,1,0); STAGE_B32(0,1,0); \
  STAGE_A(1,0,1); STAGE_B32(1,0,1); \
  VMW(8); SB; BARR; SB; \
  _Pragma("unroll 1") \
  for (int tt = 0; tt < (NT_)/2; ++tt) { \
    TILE_PHASES32(2*tt,   0, 1, NT_); \
    TILE_PHASES32(2*tt+1, 1, 0, NT_); \
  } }

__global__ __launch_bounds__(512, 2)
void down8_kernel(const unsigned short* __restrict__ H,
                  const float* __restrict__ wd,
                  const int* __restrict__ tb, const int* __restrict__ ntb,
                  const int* __restrict__ offs, const int* __restrict__ perm,
                  const float* __restrict__ wgt,
                  float* __restrict__ out)
{
  __shared__ unsigned short smem[65536];

  // grid 40 x 16 x 2 = 1280 = 5.0 exact rounds; by-major decode
  int lid = (blockIdx.z * gridDim.y + blockIdx.y) * gridDim.x + blockIdx.x;
  int sid = (lid & 7) * 160 + (lid >> 3);
  int bx = sid % MAXTB256;
  int rem = sid / MAXTB256;
  int by = rem & 15;
  int z  = rem >> 4;
  if (bx >= *ntb) return;
  int ent = tb[bx];
  int e = ent >> 16, rb = ent & 0xffff;
  int slotbase = offs[e] + rb * 256;
  int d0 = by * 128;
  int kb = z * (I_ / 2);

  int tid = threadIdx.x, lane = tid & 63, w = tid >> 6;
  int wr = w >> 2, wc = w & 3;

  // A staging (H, bf16) — unchanged proven mapping
  int cS = (lane & 7) ^ (lane >> 3);
  int rrS = 2 * (lane >> 3) + (cS >> 2);
  int kcS = (cS & 3) * 8;
  int ar0 = (w * 2 + 0) * 16 + rrS;
  const unsigned short* aptr0 = H + (size_t)(slotbase + ar0) * I_ + kcS + kb;
  const unsigned short* aptr1 = H + (size_t)(slotbase + ar0 + 16) * I_ + kcS + kb;
  // B staging (wd, fp32): sweep rows w*8+(lane>>3) and +64; chunk swizzle
  int rowS = w * 8 + (lane >> 3);
  int kfS = ((lane & 7) ^ (lane >> 3)) * 4;   // fp32 elems
  const float* bptr0 = wd + ((size_t)e * D_ + d0 + rowS) * I_ + kb + kfS;
  const float* bptr1 = wd + ((size_t)e * D_ + d0 + rowS + 64) * I_ + kb + kfS;

  int hl = (lane & 15) >> 1;
  int pA = (((lane & 1) * 4 + (lane >> 4)) ^ hl) * 8;
  int aBase = wr * 4096 + hl * 64 + pA;

  s8v af[4], bf[2];
  f32x4 acc[8][2];
#pragma unroll
  for (int m = 0; m < 8; m++)
#pragma unroll
    for (int n = 0; n < 2; n++) acc[m][n] = f32x4{0.f,0.f,0.f,0.f};

  K_LOOP32(32);   // (I_/2)/64

#pragma unroll
  for (int m = 0; m < 8; m++) {
#pragma unroll
    for (int r = 0; r < 4; r++) {
      int row = wr * 128 + m * 16 + (lane >> 4) * 4 + r;
      int s = slotbase + row;
      int tok = perm[s];
      if (tok < 0) continue;
      float wv = wgt[s];
      float* op = out + (size_t)tok * D_ + d0 + wc * 32 + (lane & 15);
#pragma unroll
      for (int n = 0; n < 2; n++)
        atomicAdd(op + n * 16, acc[m][n][r] * wv);
    }
  }
}

extern "C" void kernel_launch(void* const* d_in, const int* in_sizes, int n_in,
                              void* d_out, int out_size, void* d_ws, size_t ws_size,
                              hipStream_t stream)
{
  const float* x  = (const float*)d_in[0];
  const float* ew = (const float*)d_in[1];
  const int*  idx = (const int*)d_in[2];
  const float* wg = (const float*)d_in[4];
  const float* wu = (const float*)d_in[5];
  const float* wd = (const float*)d_in[6];
  float* out = (float*)d_out;

  char* ws = (char*)d_ws;
  int* cnt   = (int*)(ws);
  int* ntb   = (int*)(ws + 64);
  int* tb    = (int*)(ws + 128);
  int* offs  = (int*)(ws + 640);
  int* perm  = (int*)(ws + 4096);
  float* wgt = (float*)(ws + 4096 + PADMAX * 4);

  const size_t xb_off = 131072;
  const size_t xb_b   = (size_t)N_ * D_ * 2;         // 16.78 MB
  const size_t H_b    = (size_t)PADMAX * I_ * 2;     // 83.9 MB
  const size_t w_b    = (size_t)E_ * I_ * D_ * 2;    // 134.2 MB each
  unsigned short* xb  = (unsigned short*)(ws + xb_off);
  unsigned short* H   = (unsigned short*)(ws + xb_off + xb_b);
  unsigned short* wgb = (unsigned short*)(ws + xb_off + xb_b + H_b);
  unsigned short* wub = (unsigned short*)((char*)wgb + w_b);
  // no wdb — down8 reads wd fp32 directly

  hipMemsetAsync(d_out, 0, (size_t)N_ * D_ * sizeof(float), stream);
  // K1: route + x cvt + wg/wu half0 cvt
  head_kernel<<<2048, 512, 0, stream>>>(idx, ew, cnt, offs, tb, ntb, perm, wgt,
                                        x, xb, wg, wgb, wu, wub);
  // K2: gate/up GEMM on I-half0 + converts wg/wu half1 (56x16 = 896 = 3.5 rounds)
  gu8_kernel<<<dim3(MAXTB256 + CVTX, NIB), 512, 0, stream>>>(
      xb, wgb, wub, tb, ntb, offs, perm, H, 0, 1, wg, wgb, wu, wub);
  // K3: gate/up GEMM on I-half1, pure (40x16 = 640)
  gu8_kernel<<<dim3(MAXTB256, NIB), 512, 0, stream>>>(
      xb, wgb, wub, tb, ntb, offs, perm, H, I_ / 2, 0,
      (const float*)0, (unsigned short*)0, (const float*)0, (unsigned short*)0);
  // K4: down GEMM, fp32 wd direct, 40x16x2 = 1280 = 5.0 exact rounds
  down8_kernel<<<dim3(MAXTB256, 16, 2), 512, 0, stream>>>(
      H, wd, tb, ntb, offs, perm, wgt, out);
}

// Round 11
// 829.275 us; speedup vs baseline: 1.1311x; 1.1311x over previous
//
#include <hip/hip_runtime.h>
#include <hip/hip_bf16.h>
#include <math.h>

// Problem constants
#define E_ 8
#define D_ 2048
#define I_ 4096
#define TOPK_ 2
#define N_ 4096
#define NPAIR (N_*TOPK_)
#define PADMAX 10240
#define MAXTB 40
#define CVTX 12          // converter bx columns in K2/K3
#define CH_X   (1L<<20)  // x chunks (8 elems each)
#define CH_HALF (1L<<22) // per-matrix half-I chunks
#define CH_WD  (1L<<23)  // full wd chunks

typedef __attribute__((ext_vector_type(8))) short s8v;
typedef __attribute__((ext_vector_type(8))) unsigned short us8;
typedef __attribute__((ext_vector_type(4))) float f32x4;
typedef const __attribute__((address_space(1))) void* gvp;
typedef __attribute__((address_space(3))) void* lvp;

__device__ __forceinline__ unsigned short f2bf(float f) {
  union { float f; unsigned int u; } c; c.f = f;
  unsigned int u = c.u;
  u += 0x7fffu + ((u >> 16) & 1u);
  return (unsigned short)(u >> 16);
}

__device__ __forceinline__ void cvt_chunk(const float* __restrict__ src,
                                          unsigned short* __restrict__ dst,
                                          size_t off) {
  float4 a = *(const float4*)(src + off);
  float4 b = *(const float4*)(src + off + 4);
  us8 o;
  o[0]=f2bf(a.x); o[1]=f2bf(a.y); o[2]=f2bf(a.z); o[3]=f2bf(a.w);
  o[4]=f2bf(b.x); o[5]=f2bf(b.y); o[6]=f2bf(b.z); o[7]=f2bf(b.w);
  *(us8*)(dst + off) = o;
}

// convert chunk of an I-half region of a [E][I][D] matrix (ihalf = 0/1)
__device__ __forceinline__ void cvt_half(const float* __restrict__ src,
                                         unsigned short* __restrict__ dst,
                                         long chunk, int ihalf) {
  long f = chunk << 3;
  int e = (int)(f >> 22);
  long r = f & ((1L << 22) - 1);
  size_t off = ((size_t)e << 23) + ((size_t)ihalf << 22) + (size_t)r;
  cvt_chunk(src, dst, off);
}

// ---------------- Head: route (block 0) + x cvt + wg/wu half0 cvt ----------------
__global__ __launch_bounds__(512)
void head_kernel(const int* __restrict__ idx, const float* __restrict__ ew,
                 int* cnt, int* offs, int* tb, int* ntb,
                 int* perm, float* wgt,
                 const float* __restrict__ x, unsigned short* __restrict__ xb,
                 const float* __restrict__ wg, unsigned short* __restrict__ wgb,
                 const float* __restrict__ wu, unsigned short* __restrict__ wub)
{
  if (blockIdx.x == 0) {
    __shared__ int scnt[E_], soff[E_ + 1], scur[E_];
    int t = threadIdx.x;
    if (t < E_) scnt[t] = 0;
    __syncthreads();
    for (int p = t; p < NPAIR; p += blockDim.x) atomicAdd(&scnt[idx[p]], 1);
    __syncthreads();
    if (t == 0) {
      int o = 0;
      for (int e = 0; e < E_; e++) {
        soff[e] = o; scur[e] = o;
        o += ((scnt[e] + 255) / 256) * 256;
      }
      soff[E_] = o;
      int T = 0;
      for (int e = 0; e < E_; e++) {
        int nb = (scnt[e] + 255) / 256;
        for (int rb = 0; rb < nb; rb++) tb[T++] = (e << 16) | rb;
      }
      *ntb = T;
      for (int e = 0; e < E_; e++) { cnt[e] = scnt[e]; offs[e] = soff[e]; }
      offs[E_] = o;
    }
    __syncthreads();
    for (int e = 0; e < E_; e++) {
      int start = soff[e] + scnt[e], end = soff[e + 1];
      for (int s = start + t; s < end; s += blockDim.x) { perm[s] = -1; wgt[s] = 0.f; }
    }
    __syncthreads();
    for (int p = t; p < NPAIR; p += blockDim.x) {
      int e = idx[p];
      int pos = atomicAdd(&scur[e], 1);
      perm[pos] = p / TOPK_;
      wgt[pos]  = ew[p];
    }
    return;
  }
  const long TOTAL = CH_X + 2 * CH_HALF;
  long c0 = (long)(blockIdx.x - 1) * 512 + threadIdx.x;
  long stride = (long)(gridDim.x - 1) * 512;
  for (long c = c0; c < TOTAL; c += stride) {
    if (c < CH_X) cvt_chunk(x, xb, (size_t)c << 3);
    else if (c < CH_X + CH_HALF) cvt_half(wg, wgb, c - CH_X, 0);
    else cvt_half(wu, wub, c - CH_X - CH_HALF, 0);
  }
}

// =================== BK=32, 16-wave, 64 KB LDS, double-buffered GEMM ===================
// smem: ushort[32768]. A slab(P) = P*8192 [256 rows][32 k]; B slab(P) = 16384 + P*8192.
// Swizzle: 16B-chunk of logical k-chunk c for row r sits at position p = c ^ (r&3)
// (ushort off = r*32 + p*8). Staged via gl_lds linear dest: tid covers (r=tid>>2,
// p=tid&3) -> source k-chunk c = (tid&3)^(r&3). Read: lane reads (row=..+lane&15,
// c=lane>>4) at p=(lane>>4)^(lane&3) -> bijective 1KB coverage, conflict-free.
// Pipeline: STG(t+2) issued AFTER tile-t's end barrier (WAR-safe). At tile-t entry
// outstanding = {t:2, t+1:2}; VMW(2) drains t's (VMW(0) at last tile); VMW before
// BARR in every wave => slab complete for all (RAW-safe). Raw s_barrier only --
// __syncthreads would drain vmcnt(0) and kill the prefetch.

#define SB  __builtin_amdgcn_sched_barrier(0)
#define BARR __builtin_amdgcn_s_barrier()
#define VMW(N) asm volatile("s_waitcnt vmcnt(" #N ")" ::: "memory")
#define PRIO1 __builtin_amdgcn_s_setprio(1)
#define PRIO0 __builtin_amdgcn_s_setprio(0)

#define STG(T,P) { \
  __builtin_amdgcn_global_load_lds((gvp)(aptr + (size_t)(T)*32), (lvp)(&smem[(P)*8192 + w*512]), 16, 0, 0); \
  __builtin_amdgcn_global_load_lds((gvp)(bptr + (size_t)(T)*32), (lvp)(&smem[16384 + (P)*8192 + w*512]), 16, 0, 0); }

#define TILE32(T,P,NT_) { \
  if ((T) == (NT_)-1) { VMW(0); } else { VMW(2); } \
  SB; BARR; SB; \
  { const unsigned short* ap_ = &smem[(P)*8192 + aOff]; \
    const unsigned short* bp_ = &smem[16384 + (P)*8192 + bOff]; \
    s8v af[4], bf[4]; \
    af[0]=*(const s8v*)(ap_);      af[1]=*(const s8v*)(ap_+512); \
    af[2]=*(const s8v*)(ap_+1024); af[3]=*(const s8v*)(ap_+1536); \
    bf[0]=*(const s8v*)(bp_);      bf[1]=*(const s8v*)(bp_+512); \
    bf[2]=*(const s8v*)(bp_+1024); bf[3]=*(const s8v*)(bp_+1536); \
    PRIO1; \
    _Pragma("unroll") for (int m_=0;m_<4;m_++) \
      _Pragma("unroll") for (int n_=0;n_<4;n_++) \
        acc[m_][n_] = __builtin_amdgcn_mfma_f32_16x16x32_bf16(af[m_], bf[n_], acc[m_][n_], 0,0,0); \
    PRIO0; } \
  SB; BARR; SB; \
  if ((T)+2 < (NT_)) { STG((T)+2, P); } }

#define KLOOP32(NT_) { \
  STG(0,0); STG(1,1); \
  _Pragma("unroll 1") for (int tt=0; tt<(NT_)/2; ++tt) { \
    TILE32(2*tt,   0, NT_); \
    TILE32(2*tt+1, 1, NT_); } }

// ---------------- gate+up: 256 tokens x 256 vcols (128 icols x {g,u}) ----------------
// GEMM blocks bx<40; converter blocks bx>=40 (mode 1: wg/wu half1, mode 2: wd).
__global__ __launch_bounds__(1024, 4)
void gu32_kernel(const unsigned short* __restrict__ xb,
                 const unsigned short* __restrict__ wgb,
                 const unsigned short* __restrict__ wub,
                 const int* __restrict__ tb, const int* __restrict__ ntb,
                 const int* __restrict__ offs, const int* __restrict__ perm,
                 unsigned short* __restrict__ H,
                 int i_base, int cvt_mode,
                 const float* __restrict__ cs0, unsigned short* __restrict__ cd0,
                 const float* __restrict__ cs1, unsigned short* __restrict__ cd1)
{
  __shared__ unsigned short smem[32768];   // 64 KB

  int tid = threadIdx.x;
  if (blockIdx.x >= MAXTB) {
    long cid = (long)(blockIdx.x - MAXTB) + (long)CVTX * blockIdx.y;
    long c0 = cid * 1024 + tid;
    long stride = (long)CVTX * 16 * 1024;
    if (cvt_mode == 1) {
      for (long c = c0; c < 2 * CH_HALF; c += stride) {
        if (c < CH_HALF) cvt_half(cs0, cd0, c, 1);
        else cvt_half(cs1, cd1, c - CH_HALF, 1);
      }
    } else if (cvt_mode == 2) {
      for (long c = c0; c < CH_WD; c += stride) cvt_chunk(cs0, cd0, (size_t)c << 3);
    }
    return;
  }

  // XCD swizzle (by-major columns per XCD, proven round-3)
  int lid = blockIdx.y * MAXTB + blockIdx.x;
  int sid = (lid & 7) * (MAXTB * 16 / 8) + (lid >> 3);
  int bx = sid % MAXTB;
  int by = sid / MAXTB;
  if (bx >= *ntb) return;
  int ent = tb[bx];
  int e = ent >> 16, rb = ent & 0xffff;
  int slotbase = offs[e] + rb * 256;
  int i0 = i_base + by * 128;

  int lane = tid & 63, w = tid >> 6;
  int wr = w >> 2, wc = w & 3;

  // staging: thread -> (row rS, chunk-position tid&3, logical chunk cSg)
  int rS = tid >> 2;
  int cSg = (tid & 3) ^ (rS & 3);
  int tok = perm[slotbase + rS]; if (tok < 0) tok = 0;
  const unsigned short* aptr = xb + (size_t)tok * D_ + cSg * 8;
  int bmat = (rS >> 4) & 1;
  int icolS = i0 + ((rS >> 5) << 4) + (rS & 15);
  const unsigned short* bptr = (bmat ? wub : wgb) + ((size_t)e * I_ + icolS) * D_ + cSg * 8;

  // read offsets
  int rdSw = (((lane >> 4) ^ (lane & 3)) << 3);
  int aOff = wr * 2048 + (lane & 15) * 32 + rdSw;
  int bOff = wc * 2048 + (lane & 15) * 32 + rdSw;

  f32x4 acc[4][4];
#pragma unroll
  for (int m = 0; m < 4; m++)
#pragma unroll
    for (int n = 0; n < 4; n++) acc[m][n] = f32x4{0.f,0.f,0.f,0.f};

  KLOOP32(64);   // D_/32

  // epilogue: n even = gate, n odd = up of icol group 2*wc + (n>>1)
#pragma unroll
  for (int m = 0; m < 4; m++) {
#pragma unroll
    for (int r = 0; r < 4; r++) {
      int row = wr * 64 + m * 16 + (lane >> 4) * 4 + r;
      size_t hbase = (size_t)(slotbase + row) * I_ + i0 + (lane & 15);
#pragma unroll
      for (int pr = 0; pr < 2; pr++) {
        float g = acc[m][pr*2][r];
        float u = acc[m][pr*2+1][r];
        float h = (g / (1.0f + __expf(-g))) * u;
        H[hbase + (2 * wc + pr) * 16] = f2bf(h);
      }
    }
  }
}

// ---------------- down: 256 slots x 256 D-cols, weighted atomic scatter ----------------
__global__ __launch_bounds__(1024, 4)
void down32_kernel(const unsigned short* __restrict__ H,
                   const unsigned short* __restrict__ wdb,
                   const int* __restrict__ tb, const int* __restrict__ ntb,
                   const int* __restrict__ offs, const int* __restrict__ perm,
                   const float* __restrict__ wgt,
                   float* __restrict__ out)
{
  __shared__ unsigned short smem[32768];

  int tid = threadIdx.x;
  int lid = blockIdx.y * MAXTB + blockIdx.x;
  int sid = (lid & 7) * (MAXTB * 8 / 8) + (lid >> 3);
  int bx = sid % MAXTB;
  int by = sid / MAXTB;
  if (bx >= *ntb) return;
  int ent = tb[bx];
  int e = ent >> 16, rb = ent & 0xffff;
  int slotbase = offs[e] + rb * 256;
  int d0 = by * 256;

  int lane = tid & 63, w = tid >> 6;
  int wr = w >> 2, wc = w & 3;

  int rS = tid >> 2;
  int cSg = (tid & 3) ^ (rS & 3);
  const unsigned short* aptr = H + (size_t)(slotbase + rS) * I_ + cSg * 8;
  const unsigned short* bptr = wdb + ((size_t)e * D_ + d0 + rS) * I_ + cSg * 8;

  int rdSw = (((lane >> 4) ^ (lane & 3)) << 3);
  int aOff = wr * 2048 + (lane & 15) * 32 + rdSw;
  int bOff = wc * 2048 + (lane & 15) * 32 + rdSw;

  f32x4 acc[4][4];
#pragma unroll
  for (int m = 0; m < 4; m++)
#pragma unroll
    for (int n = 0; n < 4; n++) acc[m][n] = f32x4{0.f,0.f,0.f,0.f};

  KLOOP32(128);  // I_/32

#pragma unroll
  for (int m = 0; m < 4; m++) {
#pragma unroll
    for (int r = 0; r < 4; r++) {
      int row = wr * 64 + m * 16 + (lane >> 4) * 4 + r;
      int s = slotbase + row;
      int tok = perm[s];
      if (tok < 0) continue;
      float wv = wgt[s];
      float* op = out + (size_t)tok * D_ + d0 + wc * 64 + (lane & 15);
#pragma unroll
      for (int n = 0; n < 4; n++)
        atomicAdd(op + n * 16, acc[m][n][r] * wv);
    }
  }
}

extern "C" void kernel_launch(void* const* d_in, const int* in_sizes, int n_in,
                              void* d_out, int out_size, void* d_ws, size_t ws_size,
                              hipStream_t stream)
{
  const float* x  = (const float*)d_in[0];
  const float* ew = (const float*)d_in[1];
  const int*  idx = (const int*)d_in[2];
  const float* wg = (const float*)d_in[4];
  const float* wu = (const float*)d_in[5];
  const float* wd = (const float*)d_in[6];
  float* out = (float*)d_out;

  char* ws = (char*)d_ws;
  int* cnt   = (int*)(ws);
  int* ntb   = (int*)(ws + 64);
  int* tb    = (int*)(ws + 128);
  int* offs  = (int*)(ws + 640);
  int* perm  = (int*)(ws + 4096);
  float* wgt = (float*)(ws + 4096 + PADMAX * 4);

  const size_t xb_off = 131072;
  const size_t xb_b   = (size_t)N_ * D_ * 2;         // 16.78 MB
  const size_t H_b    = (size_t)PADMAX * I_ * 2;     // 83.9 MB
  const size_t w_b    = (size_t)E_ * I_ * D_ * 2;    // 134.2 MB each
  unsigned short* xb  = (unsigned short*)(ws + xb_off);
  unsigned short* H   = (unsigned short*)(ws + xb_off + xb_b);
  unsigned short* wgb = (unsigned short*)(ws + xb_off + xb_b + H_b);
  unsigned short* wub = (unsigned short*)((char*)wgb + w_b);
  unsigned short* wdb = (unsigned short*)((char*)wub + w_b);

  hipMemsetAsync(d_out, 0, (size_t)N_ * D_ * sizeof(float), stream);
  // K1: route + x cvt + wg/wu half0 cvt
  head_kernel<<<2048, 512, 0, stream>>>(idx, ew, cnt, offs, tb, ntb, perm, wgt,
                                        x, xb, wg, wgb, wu, wub);
  // K2: gate/up GEMM on I-half0 (needs wg/wu half0), converts wg/wu half1
  gu32_kernel<<<dim3(MAXTB + CVTX, 16), 1024, 0, stream>>>(
      xb, wgb, wub, tb, ntb, offs, perm, H, 0, 1, wg, wgb, wu, wub);
  // K3: gate/up GEMM on I-half1, converts wd
  gu32_kernel<<<dim3(MAXTB + CVTX, 16), 1024, 0, stream>>>(
      xb, wgb, wub, tb, ntb, offs, perm, H, I_ / 2, 2, wd, wdb,
      (const float*)0, (unsigned short*)0);
  // K4: down GEMM (40 x 8 = 320 blocks)
  down32_kernel<<<dim3(MAXTB, 8), 1024, 0, stream>>>(
      H, wdb, tb, ntb, offs, perm, wgt, out);
}

// Round 12
// 815.363 us; speedup vs baseline: 1.1504x; 1.0171x over previous
//
#include <hip/hip_runtime.h>
#include <hip/hip_bf16.h>
#include <math.h>

// Problem constants
#define E_ 8
#define D_ 2048
#define I_ 4096
#define TOPK_ 2
#define N_ 4096
#define NPAIR (N_*TOPK_)
#define PADMAX 10240
#define MAXTB 40
#define CVTX 12          // converter bx columns in K2/K3
#define CH_X   (1L<<20)  // x chunks (8 elems each)
#define CH_HALF (1L<<22) // per-matrix half-I chunks
#define CH_WD  (1L<<23)  // full wd chunks

typedef __attribute__((ext_vector_type(8))) short s8v;
typedef __attribute__((ext_vector_type(8))) unsigned short us8;
typedef __attribute__((ext_vector_type(4))) float f32x4;
typedef const __attribute__((address_space(1))) void* gvp;
typedef __attribute__((address_space(3))) void* lvp;

__device__ __forceinline__ unsigned short f2bf(float f) {
  union { float f; unsigned int u; } c; c.f = f;
  unsigned int u = c.u;
  u += 0x7fffu + ((u >> 16) & 1u);
  return (unsigned short)(u >> 16);
}

__device__ __forceinline__ void cvt_chunk(const float* __restrict__ src,
                                          unsigned short* __restrict__ dst,
                                          size_t off) {
  float4 a = *(const float4*)(src + off);
  float4 b = *(const float4*)(src + off + 4);
  us8 o;
  o[0]=f2bf(a.x); o[1]=f2bf(a.y); o[2]=f2bf(a.z); o[3]=f2bf(a.w);
  o[4]=f2bf(b.x); o[5]=f2bf(b.y); o[6]=f2bf(b.z); o[7]=f2bf(b.w);
  *(us8*)(dst + off) = o;
}

// convert chunk of an I-half region of a [E][I][D] matrix (ihalf = 0/1)
__device__ __forceinline__ void cvt_half(const float* __restrict__ src,
                                         unsigned short* __restrict__ dst,
                                         long chunk, int ihalf) {
  long f = chunk << 3;
  int e = (int)(f >> 22);
  long r = f & ((1L << 22) - 1);
  size_t off = ((size_t)e << 23) + ((size_t)ihalf << 22) + (size_t)r;
  cvt_chunk(src, dst, off);
}

// ---------------- Head: route (block 0) + x cvt + wg/wu half0 cvt ----------------
__global__ __launch_bounds__(512)
void head_kernel(const int* __restrict__ idx, const float* __restrict__ ew,
                 int* cnt, int* offs, int* tb, int* ntb,
                 int* perm, float* wgt,
                 const float* __restrict__ x, unsigned short* __restrict__ xb,
                 const float* __restrict__ wg, unsigned short* __restrict__ wgb,
                 const float* __restrict__ wu, unsigned short* __restrict__ wub)
{
  if (blockIdx.x == 0) {
    __shared__ int scnt[E_], soff[E_ + 1], scur[E_];
    int t = threadIdx.x;
    if (t < E_) scnt[t] = 0;
    __syncthreads();
    for (int p = t; p < NPAIR; p += blockDim.x) atomicAdd(&scnt[idx[p]], 1);
    __syncthreads();
    if (t == 0) {
      int o = 0;
      for (int e = 0; e < E_; e++) {
        soff[e] = o; scur[e] = o;
        o += ((scnt[e] + 255) / 256) * 256;
      }
      soff[E_] = o;
      int T = 0;
      for (int e = 0; e < E_; e++) {
        int nb = (scnt[e] + 255) / 256;
        for (int rb = 0; rb < nb; rb++) tb[T++] = (e << 16) | rb;
      }
      *ntb = T;
      for (int e = 0; e < E_; e++) { cnt[e] = scnt[e]; offs[e] = soff[e]; }
      offs[E_] = o;
    }
    __syncthreads();
    for (int e = 0; e < E_; e++) {
      int start = soff[e] + scnt[e], end = soff[e + 1];
      for (int s = start + t; s < end; s += blockDim.x) { perm[s] = -1; wgt[s] = 0.f; }
    }
    __syncthreads();
    for (int p = t; p < NPAIR; p += blockDim.x) {
      int e = idx[p];
      int pos = atomicAdd(&scur[e], 1);
      perm[pos] = p / TOPK_;
      wgt[pos]  = ew[p];
    }
    return;
  }
  const long TOTAL = CH_X + 2 * CH_HALF;
  long c0 = (long)(blockIdx.x - 1) * 512 + threadIdx.x;
  long stride = (long)(gridDim.x - 1) * 512;
  for (long c = c0; c < TOTAL; c += stride) {
    if (c < CH_X) cvt_chunk(x, xb, (size_t)c << 3);
    else if (c < CH_X + CH_HALF) cvt_half(wg, wgb, c - CH_X, 0);
    else cvt_half(wu, wub, c - CH_X - CH_HALF, 0);
  }
}

// =================== BK=32, 16-wave, 64 KB LDS, double-buffered GEMM ===================
// Slab layout = round-3 PROVEN (0 conflicts, rounds 3-9): [128 vrow][64 ushort];
// vrow v packs rows 2v,2v+1; 16B-chunk of logical chunk c=(r&1)*4+kc at position
// p = c ^ (v&7). Stage: wave w -> vrows w*8..w*8+7 (dest w*512, lane*8); source
// row = w*16 + rrS, k = kcS with cS=(lane&7)^(lane>>3), rrS=2*(lane>>3)+(cS>>2),
// kcS=(cS&3)*8. Read: row base+m*16+(lane&15), kc=lane>>4 -> hl=(lane&15)>>1,
// pA=(((lane&1)*4+(lane>>4))^hl)*8, off = base*32 + m*512 + hl*64 + pA.
// Pipeline: dbuf, VMW(2) before start-barrier (VMW(0) last), STG(t+2) after
// end-barrier (WAR-safe); raw s_barrier only.

#define SB  __builtin_amdgcn_sched_barrier(0)
#define BARR __builtin_amdgcn_s_barrier()
#define VMW(N) asm volatile("s_waitcnt vmcnt(" #N ")" ::: "memory")
#define PRIO1 __builtin_amdgcn_s_setprio(1)
#define PRIO0 __builtin_amdgcn_s_setprio(0)

#define STG(T,P) { \
  __builtin_amdgcn_global_load_lds((gvp)(aptr + (size_t)(T)*32), (lvp)(&smem[(P)*8192 + w*512]), 16, 0, 0); \
  __builtin_amdgcn_global_load_lds((gvp)(bptr + (size_t)(T)*32), (lvp)(&smem[16384 + (P)*8192 + w*512]), 16, 0, 0); }

#define TILE32(T,P,NT_) { \
  if ((T) == (NT_)-1) { VMW(0); } else { VMW(2); } \
  SB; BARR; SB; \
  { const unsigned short* ap_ = &smem[(P)*8192 + aOff]; \
    const unsigned short* bp_ = &smem[16384 + (P)*8192 + bOff]; \
    s8v af[4], bf[4]; \
    af[0]=*(const s8v*)(ap_);      af[1]=*(const s8v*)(ap_+512); \
    af[2]=*(const s8v*)(ap_+1024); af[3]=*(const s8v*)(ap_+1536); \
    bf[0]=*(const s8v*)(bp_);      bf[1]=*(const s8v*)(bp_+512); \
    bf[2]=*(const s8v*)(bp_+1024); bf[3]=*(const s8v*)(bp_+1536); \
    PRIO1; \
    _Pragma("unroll") for (int m_=0;m_<4;m_++) \
      _Pragma("unroll") for (int n_=0;n_<4;n_++) \
        acc[m_][n_] = __builtin_amdgcn_mfma_f32_16x16x32_bf16(af[m_], bf[n_], acc[m_][n_], 0,0,0); \
    PRIO0; } \
  SB; BARR; SB; \
  if ((T)+2 < (NT_)) { STG((T)+2, P); } }

#define KLOOP32(NT_) { \
  STG(0,0); STG(1,1); \
  _Pragma("unroll 1") for (int tt=0; tt<(NT_)/2; ++tt) { \
    TILE32(2*tt,   0, NT_); \
    TILE32(2*tt+1, 1, NT_); } }

// ---------------- gate+up: 256 tokens x 256 vcols (128 icols x {g,u}) ----------------
// Wave parity selects gate/up (V bit4 = w&1); read frag n parity = gate/up.
__global__ __launch_bounds__(1024, 4)
void gu32_kernel(const unsigned short* __restrict__ xb,
                 const unsigned short* __restrict__ wgb,
                 const unsigned short* __restrict__ wub,
                 const int* __restrict__ tb, const int* __restrict__ ntb,
                 const int* __restrict__ offs, const int* __restrict__ perm,
                 unsigned short* __restrict__ H,
                 int i_base, int cvt_mode,
                 const float* __restrict__ cs0, unsigned short* __restrict__ cd0,
                 const float* __restrict__ cs1, unsigned short* __restrict__ cd1)
{
  __shared__ unsigned short smem[32768];   // 64 KB

  int tid = threadIdx.x;
  if (blockIdx.x >= MAXTB) {
    long cid = (long)(blockIdx.x - MAXTB) + (long)CVTX * blockIdx.y;
    long c0 = cid * 1024 + tid;
    long stride = (long)CVTX * 16 * 1024;
    if (cvt_mode == 1) {
      for (long c = c0; c < 2 * CH_HALF; c += stride) {
        if (c < CH_HALF) cvt_half(cs0, cd0, c, 1);
        else cvt_half(cs1, cd1, c - CH_HALF, 1);
      }
    } else if (cvt_mode == 2) {
      for (long c = c0; c < CH_WD; c += stride) cvt_chunk(cs0, cd0, (size_t)c << 3);
    }
    return;
  }

  // XCD swizzle (by-major columns per XCD, proven round-3)
  int lid = blockIdx.y * MAXTB + blockIdx.x;
  int sid = (lid & 7) * (MAXTB * 16 / 8) + (lid >> 3);
  int bx = sid % MAXTB;
  int by = sid / MAXTB;
  if (bx >= *ntb) return;
  int ent = tb[bx];
  int e = ent >> 16, rb = ent & 0xffff;
  int slotbase = offs[e] + rb * 256;
  int i0 = i_base + by * 128;

  int lane = tid & 63, w = tid >> 6;
  int wr = w >> 2, wc = w & 3;

  // staging lane constants (proven round-3 mapping)
  int cS = (lane & 7) ^ (lane >> 3);
  int rrS = 2 * (lane >> 3) + (cS >> 2);
  int kcS = (cS & 3) * 8;
  int tok = perm[slotbase + w * 16 + rrS]; if (tok < 0) tok = 0;
  const unsigned short* aptr = xb + (size_t)tok * D_ + kcS;
  const unsigned short* bptr = ((w & 1) ? wub : wgb)
      + ((size_t)e * I_ + i0 + (w >> 1) * 16 + rrS) * D_ + kcS;

  // read lane constants (proven round-3 mapping)
  int hl = (lane & 15) >> 1;
  int pA = (((lane & 1) * 4 + (lane >> 4)) ^ hl) * 8;
  int aOff = wr * 2048 + hl * 64 + pA;
  int bOff = wc * 2048 + hl * 64 + pA;

  f32x4 acc[4][4];
#pragma unroll
  for (int m = 0; m < 4; m++)
#pragma unroll
    for (int n = 0; n < 4; n++) acc[m][n] = f32x4{0.f,0.f,0.f,0.f};

  KLOOP32(64);   // D_/32

  // epilogue: n even = gate, n odd = up of icol group wc*2 + (n>>1)
#pragma unroll
  for (int m = 0; m < 4; m++) {
#pragma unroll
    for (int r = 0; r < 4; r++) {
      int row = wr * 64 + m * 16 + (lane >> 4) * 4 + r;
      size_t hbase = (size_t)(slotbase + row) * I_ + i0 + (lane & 15);
#pragma unroll
      for (int pr = 0; pr < 2; pr++) {
        float g = acc[m][pr*2][r];
        float u = acc[m][pr*2+1][r];
        float h = (g / (1.0f + __expf(-g))) * u;
        H[hbase + (2 * wc + pr) * 16] = f2bf(h);
      }
    }
  }
}

// ---------------- down: 256 slots x 256 D-cols, weighted atomic scatter ----------------
__global__ __launch_bounds__(1024, 4)
void down32_kernel(const unsigned short* __restrict__ H,
                   const unsigned short* __restrict__ wdb,
                   const int* __restrict__ tb, const int* __restrict__ ntb,
                   const int* __restrict__ offs, const int* __restrict__ perm,
                   const float* __restrict__ wgt,
                   float* __restrict__ out)
{
  __shared__ unsigned short smem[32768];

  int tid = threadIdx.x;
  int lid = blockIdx.y * MAXTB + blockIdx.x;
  int sid = (lid & 7) * (MAXTB * 8 / 8) + (lid >> 3);
  int bx = sid % MAXTB;
  int by = sid / MAXTB;
  if (bx >= *ntb) return;
  int ent = tb[bx];
  int e = ent >> 16, rb = ent & 0xffff;
  int slotbase = offs[e] + rb * 256;
  int d0 = by * 256;

  int lane = tid & 63, w = tid >> 6;
  int wr = w >> 2, wc = w & 3;

  int cS = (lane & 7) ^ (lane >> 3);
  int rrS = 2 * (lane >> 3) + (cS >> 2);
  int kcS = (cS & 3) * 8;
  const unsigned short* aptr = H + (size_t)(slotbase + w * 16 + rrS) * I_ + kcS;
  const unsigned short* bptr = wdb + ((size_t)e * D_ + d0 + w * 16 + rrS) * I_ + kcS;

  int hl = (lane & 15) >> 1;
  int pA = (((lane & 1) * 4 + (lane >> 4)) ^ hl) * 8;
  int aOff = wr * 2048 + hl * 64 + pA;
  int bOff = wc * 2048 + hl * 64 + pA;

  f32x4 acc[4][4];
#pragma unroll
  for (int m = 0; m < 4; m++)
#pragma unroll
    for (int n = 0; n < 4; n++) acc[m][n] = f32x4{0.f,0.f,0.f,0.f};

  KLOOP32(128);  // I_/32

#pragma unroll
  for (int m = 0; m < 4; m++) {
#pragma unroll
    for (int r = 0; r < 4; r++) {
      int row = wr * 64 + m * 16 + (lane >> 4) * 4 + r;
      int s = slotbase + row;
      int tok = perm[s];
      if (tok < 0) continue;
      float wv = wgt[s];
      float* op = out + (size_t)tok * D_ + d0 + wc * 64 + (lane & 15);
#pragma unroll
      for (int n = 0; n < 4; n++)
        atomicAdd(op + n * 16, acc[m][n][r] * wv);
    }
  }
}

extern "C" void kernel_launch(void* const* d_in, const int* in_sizes, int n_in,
                              void* d_out, int out_size, void* d_ws, size_t ws_size,
                              hipStream_t stream)
{
  const float* x  = (const float*)d_in[0];
  const float* ew = (const float*)d_in[1];
  const int*  idx = (const int*)d_in[2];
  const float* wg = (const float*)d_in[4];
  const float* wu = (const float*)d_in[5];
  const float* wd = (const float*)d_in[6];
  float* out = (float*)d_out;

  char* ws = (char*)d_ws;
  int* cnt   = (int*)(ws);
  int* ntb   = (int*)(ws + 64);
  int* tb    = (int*)(ws + 128);
  int* offs  = (int*)(ws + 640);
  int* perm  = (int*)(ws + 4096);
  float* wgt = (float*)(ws + 4096 + PADMAX * 4);

  const size_t xb_off = 131072;
  const size_t xb_b   = (size_t)N_ * D_ * 2;         // 16.78 MB
  const size_t H_b    = (size_t)PADMAX * I_ * 2;     // 83.9 MB
  const size_t w_b    = (size_t)E_ * I_ * D_ * 2;    // 134.2 MB each
  unsigned short* xb  = (unsigned short*)(ws + xb_off);
  unsigned short* H   = (unsigned short*)(ws + xb_off + xb_b);
  unsigned short* wgb = (unsigned short*)(ws + xb_off + xb_b + H_b);
  unsigned short* wub = (unsigned short*)((char*)wgb + w_b);
  unsigned short* wdb = (unsigned short*)((char*)wub + w_b);

  hipMemsetAsync(d_out, 0, (size_t)N_ * D_ * sizeof(float), stream);
  // K1: route + x cvt + wg/wu half0 cvt
  head_kernel<<<2048, 512, 0, stream>>>(idx, ew, cnt, offs, tb, ntb, perm, wgt,
                                        x, xb, wg, wgb, wu, wub);
  // K2: gate/up GEMM on I-half0, converts wg/wu half1
  gu32_kernel<<<dim3(MAXTB + CVTX, 16), 1024, 0, stream>>>(
      xb, wgb, wub, tb, ntb, offs, perm, H, 0, 1, wg, wgb, wu, wub);
  // K3: gate/up GEMM on I-half1, converts wd
  gu32_kernel<<<dim3(MAXTB + CVTX, 16), 1024, 0, stream>>>(
      xb, wgb, wub, tb, ntb, offs, perm, H, I_ / 2, 2, wd, wdb,
      (const float*)0, (unsigned short*)0);
  // K4: down GEMM (40 x 8 = 320 blocks)
  down32_kernel<<<dim3(MAXTB, 8), 1024, 0, stream>>>(
      H, wdb, tb, ntb, offs, perm, wgt, out);
}